// Round 2
// baseline (817.594 us; speedup 1.0000x reference)
//
#include <hip/hip_runtime.h>

// B=8, F=256, T=512, D=40, S=4
#define BATCHES 8
#define NROWS (256 * 512)                 // N = F*T = 131072
#define DE 40                             // embedding dim
#define SV 4                              // assignment dim
#define GP 48                             // padded Gram dim (40 E + 4 V + 4 zero)
#define GSZ (GP * GP)                     // 2304
#define ROWS_PER_BLOCK 1024
#define CHUNKS (NROWS / ROWS_PER_BLOCK)   // 128 -> grid 1024, 4 blocks/CU
#define RSTAGE 64                         // rows per double-buffer stage
#define NSTAGES (ROWS_PER_BLOCK / RSTAGE) // 16
#define NGROUPS 8                         // K-groups (row-slices within a stage)
#define NTILES 21                         // lower-triangle 8x8 tiles of 48x48
#define NACTIVE (NGROUPS * NTILES)        // 168 compute threads
#define EF4 (RSTAGE * (DE / 4))           // 640 float4 per E stage

// async global->LDS, 16B per lane. LDS dest must be wave-uniform base + lane*16,
// which our contiguous pitch-40 E tile and pitch-4 V tile satisfy.
__device__ __forceinline__ void async_copy16(const float4* g, float4* s) {
    __builtin_amdgcn_global_load_lds(
        (const __attribute__((address_space(1))) void*)g,
        (__attribute__((address_space(3))) void*)s,
        16, 0, 0);
}

__global__ __launch_bounds__(256, 4) void gram_kernel(const float* __restrict__ E,
                                                      const float* __restrict__ V,
                                                      float* __restrict__ G) {
    __shared__ float etile[2][RSTAGE][DE]; // pitch 40 floats (NO pad: global_load_lds contiguity)
    __shared__ float vtile[2][RSTAGE][SV];
    __shared__ float gsum[GSZ];

    const int tid = threadIdx.x;
    const int b = blockIdx.x / CHUNKS;
    const int chunk = blockIdx.x % CHUNKS;
    const size_t row0 = (size_t)chunk * ROWS_PER_BLOCK;

    const float4* __restrict__ Eg = (const float4*)(E + (size_t)b * NROWS * DE); // 10 f4/row
    const float4* __restrict__ Vg = (const float4*)(V + (size_t)b * NROWS * SV); // 1 f4/row

    for (int i = tid; i < GSZ; i += 256) gsum[i] = 0.f;

    // thread -> (K-group, lower-triangle tile)
    const int grp = tid / NTILES;
    const int tt = tid % NTILES;
    const bool active = (tid < NACTIVE);
    int ti = 0;
    while ((ti + 1) * (ti + 2) / 2 <= tt) ti++;  // tt = ti*(ti+1)/2 + tj, tj<=ti
    const int tj = tt - ti * (ti + 1) / 2;

    float acc[8][8];
    #pragma unroll
    for (int i = 0; i < 8; ++i)
        #pragma unroll
        for (int j = 0; j < 8; ++j) acc[i][j] = 0.f;

    // prologue: stage 0 -> buf 0
    {
        const float4* eg = Eg + row0 * (DE / 4);
        float4* el = (float4*)&etile[0][0][0];
        #pragma unroll
        for (int it = 0; it < 3; ++it) {
            const int idx = tid + it * 256;
            if (idx < EF4) async_copy16(eg + idx, el + idx);
        }
        if (tid < RSTAGE) async_copy16(Vg + row0 + tid, (float4*)&vtile[0][0][0] + tid);
    }

    int buf = 0;
    for (int s = 0; s < NSTAGES; ++s) {
        __syncthreads();  // drains vmcnt: buf ready; buf^1 free to overwrite
        if (s + 1 < NSTAGES) {  // prefetch next stage while computing this one
            const size_t rb = row0 + (size_t)(s + 1) * RSTAGE;
            const float4* eg = Eg + rb * (DE / 4);
            float4* el = (float4*)&etile[buf ^ 1][0][0];
            #pragma unroll
            for (int it = 0; it < 3; ++it) {
                const int idx = tid + it * 256;
                if (idx < EF4) async_copy16(eg + idx, el + idx);
            }
            if (tid < RSTAGE) async_copy16(Vg + rb + tid, (float4*)&vtile[buf ^ 1][0][0] + tid);
        }
        if (active) {
            #pragma unroll
            for (int k = 0; k < RSTAGE / NGROUPS; ++k) {
                const int r = grp + k * NGROUPS;
                float4 xa, ya, xb, yb;
                if (ti < 5) {
                    xa = *(const float4*)&etile[buf][r][8 * ti];
                    ya = *(const float4*)&etile[buf][r][8 * ti + 4];
                } else {
                    xa = *(const float4*)&vtile[buf][r][0];  // cols 40..43; 44..47 zero
                    ya = make_float4(0.f, 0.f, 0.f, 0.f);
                }
                if (tj < 5) {
                    xb = *(const float4*)&etile[buf][r][8 * tj];
                    yb = *(const float4*)&etile[buf][r][8 * tj + 4];
                } else {
                    xb = *(const float4*)&vtile[buf][r][0];
                    yb = make_float4(0.f, 0.f, 0.f, 0.f);
                }
                const float av[8] = {xa.x, xa.y, xa.z, xa.w, ya.x, ya.y, ya.z, ya.w};
                const float bv[8] = {xb.x, xb.y, xb.z, xb.w, yb.x, yb.y, yb.z, yb.w};
                #pragma unroll
                for (int i = 0; i < 8; ++i)
                    #pragma unroll
                    for (int j = 0; j < 8; ++j)
                        acc[i][j] += av[i] * bv[j];
            }
        }
        buf ^= 1;
    }

    // cross-K-group reduction in LDS (ds_add_f32), then one atomic set per block
    __syncthreads();
    if (active) {
        const int gi0 = 8 * ti, gj0 = 8 * tj;
        #pragma unroll
        for (int i = 0; i < 8; ++i)
            #pragma unroll
            for (int j = 0; j < 8; ++j)
                if (ti != tj || i >= j)  // diagonal tiles: keep lower triangle only
                    atomicAdd(&gsum[(gi0 + i) * GP + (gj0 + j)], acc[i][j]);
    }
    __syncthreads();

    float* Gb = G + (size_t)b * GSZ;
    for (int idx = tid; idx < GSZ; idx += 256) {
        const int gi = idx / GP, gj = idx % GP;
        if (gj <= gi && gi < (DE + SV)) atomicAdd(&Gb[idx], gsum[idx]);
    }
}

// out = sum_b sum_{i>=j} w * sign * G[b][i][j]^2 / (B*N), w = 1 on diag else 2,
// sign = +1 if i,j in same block (EE or VV), -1 if mixed.
__global__ __launch_bounds__(256) void finish_kernel(const float* __restrict__ G,
                                                     float* __restrict__ out) {
    const int tid = threadIdx.x;
    float sum = 0.f;
    for (int idx = tid; idx < BATCHES * GSZ; idx += 256) {
        const int ij = idx % GSZ;
        const int gi = ij / GP;
        const int gj = ij % GP;
        if (gj > gi || gi >= (DE + SV)) continue;
        const float g = G[idx];
        const float w = (gi == gj) ? 1.f : 2.f;
        const float sgn = ((gi < DE) == (gj < DE)) ? 1.f : -1.f;
        sum += w * sgn * g * g;
    }
    #pragma unroll
    for (int o = 32; o > 0; o >>= 1) sum += __shfl_down(sum, o, 64);
    __shared__ float ws[4];
    if ((tid & 63) == 0) ws[tid >> 6] = sum;
    __syncthreads();
    if (tid == 0) {
        const float t = ws[0] + ws[1] + ws[2] + ws[3];
        out[0] = t / (float)((size_t)BATCHES * NROWS);
    }
}

extern "C" void kernel_launch(void* const* d_in, const int* in_sizes, int n_in,
                              void* d_out, int out_size, void* d_ws, size_t ws_size,
                              hipStream_t stream) {
    const float* E = (const float*)d_in[0];   // embeddings (B,F,T,D) fp32
    const float* V = (const float*)d_in[1];   // assignments (B,F,T,S) fp32
    float* G = (float*)d_ws;                  // B * 48*48 fp32 Gram accumulators

    hipMemsetAsync(G, 0, (size_t)BATCHES * GSZ * sizeof(float), stream);
    gram_kernel<<<BATCHES * CHUNKS, 256, 0, stream>>>(E, V, G);
    finish_kernel<<<1, 256, 0, stream>>>(G, (float*)d_out);
}

// Round 3
// 436.560 us; speedup vs baseline: 1.8728x; 1.8728x over previous
//
#include <hip/hip_runtime.h>

// B=8, F=256, T=512, D=40, S=4
#define BATCHES 8
#define NROWS (256 * 512)                 // N = F*T = 131072
#define DE 40                             // embedding dim
#define SV 4                              // assignment dim
#define GP 48                             // padded Gram dim (40 E + 4 V + 4 zero)
#define GSZ (GP * GP)                     // 2304
#define ROWS_PER_BLOCK 1024
#define CHUNKS (NROWS / ROWS_PER_BLOCK)   // 128 -> grid 1024, 4 blocks/CU
#define RSTAGE 64                         // rows per double-buffer stage
#define NSTAGES (ROWS_PER_BLOCK / RSTAGE) // 16
#define NGROUPS 4                         // K-groups (row-slices within a stage)
#define NTILES 42                         // 8x4 tiles touching lower triangle of 48x48
#define NACTIVE (NGROUPS * NTILES)        // 168 compute threads
#define EF4 (RSTAGE * (DE / 4))           // 640 float4 per E stage

// async global->LDS, 16B/lane. LDS dest = wave-uniform base + lane*16 (satisfied:
// contiguous pitch-40 E tile, pitch-4 V tile, idx = tid + it*256).
__device__ __forceinline__ void async_copy16(const float4* g, float4* s) {
    __builtin_amdgcn_global_load_lds(
        (const __attribute__((address_space(1))) void*)g,
        (__attribute__((address_space(3))) void*)s,
        16, 0, 0);
}

// acc tile = 8 rows x 4 cols => 32 floats/thread. No min-waves hint: R2 showed
// __launch_bounds__(256,4) + 64-float acc => full accumulator spill (1.27 GB
// scratch writes). ~75 VGPRs here fits any reasonable allocation.
__global__ __launch_bounds__(256) void gram_kernel(const float* __restrict__ E,
                                                   const float* __restrict__ V,
                                                   float* __restrict__ G) {
    __shared__ float etile[2][RSTAGE][DE]; // pitch 40 (no pad: global_load_lds contiguity)
    __shared__ float vtile[2][RSTAGE][SV];
    __shared__ float gsum[GSZ];

    const int tid = threadIdx.x;
    const int b = blockIdx.x / CHUNKS;
    const int chunk = blockIdx.x % CHUNKS;
    const size_t row0 = (size_t)chunk * ROWS_PER_BLOCK;

    const float4* __restrict__ Eg = (const float4*)(E + (size_t)b * NROWS * DE); // 10 f4/row
    const float4* __restrict__ Vg = (const float4*)(V + (size_t)b * NROWS * SV); // 1 f4/row

    for (int i = tid; i < GSZ; i += 256) gsum[i] = 0.f;

    // thread -> (K-group, tile). Tile (ti,tj): rows 8ti..8ti+7, cols 4tj..4tj+3,
    // kept iff 4tj <= 8ti+7 (touches lower triangle). Count per ti = 2ti+2, total 42.
    // tt -> ti: base(ti) = ti^2 + ti.
    const int grp = tid / NTILES;        // 0..3 for active threads
    const int tt = tid % NTILES;
    const bool active = (tid < NACTIVE);
    int ti = 0;
    while ((ti + 1) * (ti + 1) + (ti + 1) <= tt) ti++;
    const int tj = tt - (ti * ti + ti);

    float acc[8][4];
    #pragma unroll
    for (int i = 0; i < 8; ++i)
        #pragma unroll
        for (int j = 0; j < 4; ++j) acc[i][j] = 0.f;

    // prologue: stage 0 -> buf 0
    {
        const float4* eg = Eg + row0 * (DE / 4);
        float4* el = (float4*)&etile[0][0][0];
        #pragma unroll
        for (int it = 0; it < 3; ++it) {
            const int idx = tid + it * 256;
            if (idx < EF4) async_copy16(eg + idx, el + idx);
        }
        if (tid < RSTAGE) async_copy16(Vg + row0 + tid, (float4*)&vtile[0][0][0] + tid);
    }

    int buf = 0;
    for (int s = 0; s < NSTAGES; ++s) {
        __syncthreads();  // drains vmcnt: buf ready; buf^1 free to overwrite
        if (s + 1 < NSTAGES) {  // prefetch next stage while computing this one
            const size_t rb = row0 + (size_t)(s + 1) * RSTAGE;
            const float4* eg = Eg + rb * (DE / 4);
            float4* el = (float4*)&etile[buf ^ 1][0][0];
            #pragma unroll
            for (int it = 0; it < 3; ++it) {
                const int idx = tid + it * 256;
                if (idx < EF4) async_copy16(eg + idx, el + idx);
            }
            if (tid < RSTAGE) async_copy16(Vg + rb + tid, (float4*)&vtile[buf ^ 1][0][0] + tid);
        }
        if (active) {
            #pragma unroll
            for (int k = 0; k < RSTAGE / NGROUPS; ++k) {
                const int r = grp + k * NGROUPS;
                float4 xa, ya, xb;
                if (ti < 5) {  // a rows 8ti..8ti+7 from E
                    xa = *(const float4*)&etile[buf][r][8 * ti];
                    ya = *(const float4*)&etile[buf][r][8 * ti + 4];
                } else {       // rows 40..43 = V, 44..47 = zero pad
                    xa = *(const float4*)&vtile[buf][r][0];
                    ya = make_float4(0.f, 0.f, 0.f, 0.f);
                }
                if (tj < 10)      xb = *(const float4*)&etile[buf][r][4 * tj];
                else if (tj == 10) xb = *(const float4*)&vtile[buf][r][0];
                else              xb = make_float4(0.f, 0.f, 0.f, 0.f);
                const float av[8] = {xa.x, xa.y, xa.z, xa.w, ya.x, ya.y, ya.z, ya.w};
                const float bv[4] = {xb.x, xb.y, xb.z, xb.w};
                #pragma unroll
                for (int i = 0; i < 8; ++i)
                    #pragma unroll
                    for (int j = 0; j < 4; ++j)
                        acc[i][j] += av[i] * bv[j];
            }
        }
        buf ^= 1;
    }

    // Atomic-free cross-K-group merge: one group per round, tiles disjoint within
    // a round, barrier between rounds. Keep lower-triangle entries only.
    #pragma unroll
    for (int g = 0; g < NGROUPS; ++g) {
        __syncthreads();
        if (active && grp == g) {
            #pragma unroll
            for (int i = 0; i < 8; ++i)
                #pragma unroll
                for (int j = 0; j < 4; ++j) {
                    const int gi = 8 * ti + i, gj = 4 * tj + j;
                    if (gi >= gj) gsum[gi * GP + gj] += acc[i][j];
                }
        }
    }
    __syncthreads();

    float* Gb = G + (size_t)b * GSZ;
    for (int idx = tid; idx < GSZ; idx += 256) {
        const int gi = idx / GP, gj = idx % GP;
        if (gj <= gi && gi < (DE + SV)) atomicAdd(&Gb[idx], gsum[idx]);  // 990/block
    }
}

// out = sum_b sum_{i>=j} w * sign * G[b][i][j]^2 / (B*N), w = 1 on diag else 2,
// sign = +1 if i,j in same block (EE or VV), -1 if mixed (V-row x E-col).
__global__ __launch_bounds__(256) void finish_kernel(const float* __restrict__ G,
                                                     float* __restrict__ out) {
    const int tid = threadIdx.x;
    float sum = 0.f;
    for (int idx = tid; idx < BATCHES * GSZ; idx += 256) {
        const int ij = idx % GSZ;
        const int gi = ij / GP;
        const int gj = ij % GP;
        if (gj > gi || gi >= (DE + SV)) continue;
        const float g = G[idx];
        const float w = (gi == gj) ? 1.f : 2.f;
        const float sgn = ((gi < DE) == (gj < DE)) ? 1.f : -1.f;
        sum += w * sgn * g * g;
    }
    #pragma unroll
    for (int o = 32; o > 0; o >>= 1) sum += __shfl_down(sum, o, 64);
    __shared__ float ws[4];
    if ((tid & 63) == 0) ws[tid >> 6] = sum;
    __syncthreads();
    if (tid == 0) {
        const float t = ws[0] + ws[1] + ws[2] + ws[3];
        out[0] = t / (float)((size_t)BATCHES * NROWS);
    }
}

extern "C" void kernel_launch(void* const* d_in, const int* in_sizes, int n_in,
                              void* d_out, int out_size, void* d_ws, size_t ws_size,
                              hipStream_t stream) {
    const float* E = (const float*)d_in[0];   // embeddings (B,F,T,D) fp32
    const float* V = (const float*)d_in[1];   // assignments (B,F,T,S) fp32
    float* G = (float*)d_ws;                  // B * 48*48 fp32 Gram accumulators

    hipMemsetAsync(G, 0, (size_t)BATCHES * GSZ * sizeof(float), stream);
    gram_kernel<<<BATCHES * CHUNKS, 256, 0, stream>>>(E, V, G);
    finish_kernel<<<1, 256, 0, stream>>>(G, (float*)d_out);
}

// Round 4
// 278.421 us; speedup vs baseline: 2.9365x; 1.5680x over previous
//
#include <hip/hip_runtime.h>

// B=8, F=256, T=512, D=40, S=4
#define BATCHES 8
#define NROWS (256 * 512)                 // N = F*T = 131072
#define DE 40                             // embedding dim
#define SV 4                              // assignment dim
#define GP 48                             // padded Gram dim (40 E + 4 V + 4 zero)
#define GSZ (GP * GP)                     // 2304
#define TP 48                             // LDS tile pitch (floats): E 0..39, V 40..43, 0-pad 44..47
#define ROWS_PER_BLOCK 1024
#define CHUNKS (NROWS / ROWS_PER_BLOCK)   // 128 -> grid 1024, 4 blocks/CU
#define RSTAGE 64
#define NSTAGES (ROWS_PER_BLOCK / RSTAGE) // 16
#define NGROUPS 4                         // K-groups
#define NTILES 42                         // 8x4 tiles touching lower triangle of 48x48
#define NACTIVE (NGROUPS * NTILES)        // 168
#define EF4 (RSTAGE * (DE / 4))           // 640 E float4 per stage
#define CPY (EF4 + RSTAGE)                // 704 float4 copies per stage

// Branchless lean kernel: R3's VGPR=152 (2 waves/SIMD, 11.6% occ) came from
// branches inside the unrolled k-loop. Cap at 128 VGPRs (4 waves/SIMD).
__global__ __launch_bounds__(256, 4) void gram_kernel(const float* __restrict__ E,
                                                      const float* __restrict__ V,
                                                      float* __restrict__ G) {
    __shared__ float tile[2][RSTAGE][TP];
    __shared__ float gsum[GSZ];

    const int tid = threadIdx.x;
    const int b = blockIdx.x / CHUNKS;
    const int chunk = blockIdx.x % CHUNKS;
    const size_t row0 = (size_t)chunk * ROWS_PER_BLOCK;

    const float4* __restrict__ Eg = (const float4*)(E + (size_t)b * NROWS * DE) + row0 * (DE / 4);
    const float4* __restrict__ Vg = (const float4*)(V + (size_t)b * NROWS * SV) + row0;

    for (int i = tid; i < GSZ; i += 256) gsum[i] = 0.f;
    // zero the pad cols 44..47 of every row, both buffers (written once, read every stage)
    if (tid < 2 * RSTAGE) {
        const int bb = tid / RSTAGE, r = tid % RSTAGE;
        *(float4*)&tile[bb][r][44] = make_float4(0.f, 0.f, 0.f, 0.f);
    }

    // Precompute this thread's 3 copy slots (constant across stages).
    // slot idx < EF4: E float4 #idx -> row idx/10, col4 idx%10. Else V f4 -> row idx-EF4, col 40.
    int ldsoff[3];  // float offset within tile[buf]
    int goff[3];    // float4 offset: E-slots from Eg, V-slots from Vg
    bool isv[3], valid[3];
    #pragma unroll
    for (int it = 0; it < 3; ++it) {
        const int idx = tid + it * 256;
        valid[it] = (idx < CPY);
        isv[it] = (idx >= EF4);
        if (idx < EF4) { ldsoff[it] = (idx / 10) * TP + (idx % 10) * 4; goff[it] = idx; }
        else           { const int r = idx - EF4; ldsoff[it] = r * TP + DE; goff[it] = r; }
    }

    // thread -> (K-group, tile). Tile (ti,tj): Gram rows 8ti..8ti+7, cols 4tj..4tj+3,
    // kept iff 4tj <= 8ti+7. Per-ti count 2ti+2, base ti^2+ti, total 42.
    const int grp = tid / NTILES;
    const int tt = tid % NTILES;
    const bool active = (tid < NACTIVE);
    int ti = 0;
    while ((ti + 1) * (ti + 1) + (ti + 1) <= tt) ti++;
    const int tj = tt - (ti * ti + ti);

    float acc[8][4];
    #pragma unroll
    for (int i = 0; i < 8; ++i)
        #pragma unroll
        for (int j = 0; j < 4; ++j) acc[i][j] = 0.f;

    // prologue: stage 0 -> regs
    float4 c0, c1, c2;
    {
        if (valid[0]) c0 = isv[0] ? Vg[goff[0]] : Eg[goff[0]];
        if (valid[1]) c1 = isv[1] ? Vg[goff[1]] : Eg[goff[1]];
        if (valid[2]) c2 = isv[2] ? Vg[goff[2]] : Eg[goff[2]];
    }

    int buf = 0;
    for (int s = 0; s < NSTAGES; ++s) {
        // regs -> tile[buf] (waits on the loads issued last iteration)
        if (valid[0]) *(float4*)&tile[buf][0][ldsoff[0]] = c0;
        if (valid[1]) *(float4*)&tile[buf][0][ldsoff[1]] = c1;
        if (valid[2]) *(float4*)&tile[buf][0][ldsoff[2]] = c2;
        // issue loads for stage s+1 (consumed at next iteration's ds_write)
        if (s + 1 < NSTAGES) {
            const int e4 = (s + 1) * EF4, v4 = (s + 1) * RSTAGE;
            if (valid[0]) c0 = isv[0] ? Vg[v4 + goff[0]] : Eg[e4 + goff[0]];
            if (valid[1]) c1 = isv[1] ? Vg[v4 + goff[1]] : Eg[e4 + goff[1]];
            if (valid[2]) c2 = isv[2] ? Vg[v4 + goff[2]] : Eg[e4 + goff[2]];
        }
        __syncthreads();  // tile[buf] staged; safe: W(s+2) to this buf is 2 barriers away

        if (active) {
            const float* ap = &tile[buf][0][8 * ti];   // uniform pitch-TP, branchless
            const float* bp = &tile[buf][0][4 * tj];
            #pragma unroll 4
            for (int k = 0; k < RSTAGE / NGROUPS; ++k) {
                const int r = (grp + k * NGROUPS) * TP;
                const float4 xa = *(const float4*)(ap + r);
                const float4 ya = *(const float4*)(ap + r + 4);
                const float4 xb = *(const float4*)(bp + r);
                const float av[8] = {xa.x, xa.y, xa.z, xa.w, ya.x, ya.y, ya.z, ya.w};
                const float bv[4] = {xb.x, xb.y, xb.z, xb.w};
                #pragma unroll
                for (int i = 0; i < 8; ++i)
                    #pragma unroll
                    for (int j = 0; j < 4; ++j)
                        acc[i][j] += av[i] * bv[j];
            }
        }
        buf ^= 1;
        __syncthreads();  // compute(s) done before anyone writes this buf again
    }

    // Atomic-free cross-K-group merge: one group per round, tiles disjoint in a round.
    #pragma unroll
    for (int g = 0; g < NGROUPS; ++g) {
        if (active && grp == g) {
            #pragma unroll
            for (int i = 0; i < 8; ++i)
                #pragma unroll
                for (int j = 0; j < 4; ++j) {
                    const int gi = 8 * ti + i, gj = 4 * tj + j;
                    if (gi >= gj) gsum[gi * GP + gj] += acc[i][j];
                }
        }
        __syncthreads();
    }

    float* Gb = G + (size_t)b * GSZ;
    for (int idx = tid; idx < GSZ; idx += 256) {
        const int gi = idx / GP, gj = idx % GP;
        if (gj <= gi && gi < (DE + SV)) atomicAdd(&Gb[idx], gsum[idx]);  // 990/block
    }
}

// out = sum_b sum_{i>=j} w * sign * G[b][i][j]^2 / (B*N); w=1 diag else 2;
// sign=+1 same block (EE/VV), -1 mixed.
__global__ __launch_bounds__(256) void finish_kernel(const float* __restrict__ G,
                                                     float* __restrict__ out) {
    const int tid = threadIdx.x;
    float sum = 0.f;
    for (int idx = tid; idx < BATCHES * GSZ; idx += 256) {
        const int ij = idx % GSZ;
        const int gi = ij / GP;
        const int gj = ij % GP;
        if (gj > gi || gi >= (DE + SV)) continue;
        const float g = G[idx];
        const float w = (gi == gj) ? 1.f : 2.f;
        const float sgn = ((gi < DE) == (gj < DE)) ? 1.f : -1.f;
        sum += w * sgn * g * g;
    }
    #pragma unroll
    for (int o = 32; o > 0; o >>= 1) sum += __shfl_down(sum, o, 64);
    __shared__ float ws[4];
    if ((tid & 63) == 0) ws[tid >> 6] = sum;
    __syncthreads();
    if (tid == 0) {
        const float t = ws[0] + ws[1] + ws[2] + ws[3];
        out[0] = t / (float)((size_t)BATCHES * NROWS);
    }
}

extern "C" void kernel_launch(void* const* d_in, const int* in_sizes, int n_in,
                              void* d_out, int out_size, void* d_ws, size_t ws_size,
                              hipStream_t stream) {
    const float* E = (const float*)d_in[0];   // embeddings (B,F,T,D) fp32
    const float* V = (const float*)d_in[1];   // assignments (B,F,T,S) fp32
    float* G = (float*)d_ws;                  // B * 48*48 fp32 Gram accumulators

    hipMemsetAsync(G, 0, (size_t)BATCHES * GSZ * sizeof(float), stream);
    gram_kernel<<<BATCHES * CHUNKS, 256, 0, stream>>>(E, V, G);
    finish_kernel<<<1, 256, 0, stream>>>(G, (float*)d_out);
}

// Round 5
// 269.066 us; speedup vs baseline: 3.0386x; 1.0348x over previous
//
#include <hip/hip_runtime.h>
#include <hip/hip_bf16.h>

// B=8, F=256, T=512, D=40, S=4
#define BATCHES 8
#define NROWS (256 * 512)                 // N = F*T = 131072
#define DE 40
#define SV 4
#define GP 48                             // Gram dim: 40 E + 4 V + 4 zero pad
#define GSZ (GP * GP)                     // 2304
#define ROWS_PER_BLOCK 1024
#define CHUNKS (NROWS / ROWS_PER_BLOCK)   // 128 -> grid 1024, 4 blocks/CU
#define RSTAGE 128                        // rows per stage (4 waves x K=32)
#define NSTAGES (ROWS_PER_BLOCK / RSTAGE) // 8
#define COLBYTES 256                      // RSTAGE * 2 B (bf16), column-major tile
#define TILEBYTES (GP * COLBYTES)         // 12288 per buffer
#define NSLOT 352                         // 11 col-groups (10 E f4 + 1 V f4) x 32 row-groups

typedef __attribute__((ext_vector_type(8))) short bf16x8;  // MFMA A/B frag
typedef __attribute__((ext_vector_type(4))) float f32x4;   // MFMA C/D frag
typedef __attribute__((ext_vector_type(2))) int i32x2;     // 4 bf16 packed

__device__ __forceinline__ int pk_bf16(float lo, float hi) {
    __hip_bfloat162 h2 = __float22bfloat162_rn(float2{lo, hi});  // RNE, packed cvt
    return *reinterpret_cast<int*>(&h2);  // lo in bits 0..15
}

// Gram via mfma_f32_16x16x32_bf16. LDS tile: col-major bf16 [48 cols][128 rows],
// K-rotation swizzle: phys_kbyte = (kbyte + 16*(col&15)) & 255 -> frag reads
// (lane i reads col 16t+i) hit 16 distinct bank-starts per quad = conflict-free.
__global__ __launch_bounds__(256, 4) void gram_kernel(const float* __restrict__ E,
                                                      const float* __restrict__ V,
                                                      float* __restrict__ G) {
    __shared__ __align__(16) char tb[2][TILEBYTES];
    __shared__ float gsum[GSZ];

    const int tid = threadIdx.x;
    const int lane = tid & 63;
    const int wave = tid >> 6;            // K-chunk: rows 32*wave..32*wave+31 of stage
    const int b = blockIdx.x / CHUNKS;
    const int chunk = blockIdx.x % CHUNKS;
    const size_t row0 = (size_t)chunk * ROWS_PER_BLOCK;

    const float4* __restrict__ Eg = (const float4*)(E + (size_t)b * NROWS * DE) + row0 * 10;
    const float4* __restrict__ Vg = (const float4*)(V + (size_t)b * NROWS * SV) + row0;

    for (int i = tid; i < GSZ; i += 256) gsum[i] = 0.f;
    if (tid < 128) {  // zero pad cols 44..47, both buffers (constant all stages)
        const int bb = tid >> 6, off = (tid & 63) * 16;
        *(float4*)&tb[bb][44 * COLBYTES + off] = make_float4(0.f, 0.f, 0.f, 0.f);
    }

    // Staging slots: slot s -> cg = s%11 (0..9: E float4-col, 10: V), rg = s/11,
    // rows 4rg..4rg+3. Thread owns slot tid, and tid+256 if tid<96.
    const int cgA = tid % 11, rgA = tid / 11;
    const int cgB = (tid + 256) % 11, rgB = (tid + 256) / 11;
    const bool hasB = (tid < 96);
    const bool vA = (cgA == 10), vB = (cgB == 10);
    const int pA = vA ? 1 : 10, cA = vA ? 0 : cgA;     // row pitch (f4), col (f4)
    const int pB = vB ? 1 : 10, cB = vB ? 0 : cgB;
    const float4* __restrict__ gA = vA ? Vg : Eg;
    const float4* __restrict__ gB = vB ? Vg : Eg;
    const int oA = 4 * rgA * pA + cA;
    const int oB = 4 * rgB * pB + cB;

    f32x4 acc[6];  // lower-tri 16x16 tiles: (0,0)(1,0)(1,1)(2,0)(2,1)(2,2)
    #pragma unroll
    for (int i = 0; i < 6; ++i) acc[i] = (f32x4){0.f, 0.f, 0.f, 0.f};

    float4 a0, a1, a2, a3, b0, b1, b2, b3;
    a0 = gA[oA]; a1 = gA[oA + pA]; a2 = gA[oA + 2 * pA]; a3 = gA[oA + 3 * pA];
    if (hasB) { b0 = gB[oB]; b1 = gB[oB + pB]; b2 = gB[oB + 2 * pB]; b3 = gB[oB + 3 * pB]; }

    const int fcol = lane & 15;           // frag col offset (n / m index)
    const int fq = lane >> 4;             // frag quad (k-subgroup)
    const int foff = ((wave * 64 + fq * 16) + 16 * fcol) & 255;  // swizzled k-byte

    int buf = 0;
    for (int s = 0; s < NSTAGES; ++s) {
        __syncthreads();  // compute on this buf (stage s-2) done -> writable
        {   // transpose 4x4 fp32 -> bf16, col-major b64 writes
            char* base = tb[buf];
            #pragma unroll
            for (int j = 0; j < 4; ++j) {
                const float f0 = (j == 0) ? a0.x : (j == 1) ? a0.y : (j == 2) ? a0.z : a0.w;
                const float f1 = (j == 0) ? a1.x : (j == 1) ? a1.y : (j == 2) ? a1.z : a1.w;
                const float f2 = (j == 0) ? a2.x : (j == 1) ? a2.y : (j == 2) ? a2.z : a2.w;
                const float f3 = (j == 0) ? a3.x : (j == 1) ? a3.y : (j == 2) ? a3.z : a3.w;
                const int col = 4 * cgA + j;
                const int off = (8 * rgA + 16 * (col & 15)) & 255;
                i32x2 p = { pk_bf16(f0, f1), pk_bf16(f2, f3) };
                *(i32x2*)&base[col * COLBYTES + off] = p;
            }
            if (hasB) {
                #pragma unroll
                for (int j = 0; j < 4; ++j) {
                    const float f0 = (j == 0) ? b0.x : (j == 1) ? b0.y : (j == 2) ? b0.z : b0.w;
                    const float f1 = (j == 0) ? b1.x : (j == 1) ? b1.y : (j == 2) ? b1.z : b1.w;
                    const float f2 = (j == 0) ? b2.x : (j == 1) ? b2.y : (j == 2) ? b2.z : b2.w;
                    const float f3 = (j == 0) ? b3.x : (j == 1) ? b3.y : (j == 2) ? b3.z : b3.w;
                    const int col = 4 * cgB + j;
                    const int off = (8 * rgB + 16 * (col & 15)) & 255;
                    i32x2 p = { pk_bf16(f0, f1), pk_bf16(f2, f3) };
                    *(i32x2*)&base[col * COLBYTES + off] = p;
                }
            }
        }
        if (s + 1 < NSTAGES) {  // prefetch next stage into regs; overlaps MFMA below
            const int adv = (s + 1) * RSTAGE;
            a0 = gA[oA + adv * pA]; a1 = gA[oA + (adv + 1 * 4 / 4) * 0 + oA * 0 + (oA + adv * pA + pA) - (oA + adv * pA)];  // placeholder avoided
            a0 = gA[oA + adv * pA];
            a1 = gA[oA + adv * pA + pA];
            a2 = gA[oA + adv * pA + 2 * pA];
            a3 = gA[oA + adv * pA + 3 * pA];
            if (hasB) {
                b0 = gB[oB + adv * pB];
                b1 = gB[oB + adv * pB + pB];
                b2 = gB[oB + adv * pB + 2 * pB];
                b3 = gB[oB + adv * pB + 3 * pB];
            }
        }
        __syncthreads();  // tile[buf] fully staged

        {   // 3 frag loads + 6 MFMAs per wave; frags serve as both A and B
            const char* base = tb[buf];
            const bf16x8 f0 = *(const bf16x8*)&base[(0 * 16 + fcol) * COLBYTES + foff];
            const bf16x8 f1 = *(const bf16x8*)&base[(1 * 16 + fcol) * COLBYTES + foff];
            const bf16x8 f2 = *(const bf16x8*)&base[(2 * 16 + fcol) * COLBYTES + foff];
            acc[0] = __builtin_amdgcn_mfma_f32_16x16x32_bf16(f0, f0, acc[0], 0, 0, 0);
            acc[1] = __builtin_amdgcn_mfma_f32_16x16x32_bf16(f1, f0, acc[1], 0, 0, 0);
            acc[2] = __builtin_amdgcn_mfma_f32_16x16x32_bf16(f1, f1, acc[2], 0, 0, 0);
            acc[3] = __builtin_amdgcn_mfma_f32_16x16x32_bf16(f2, f0, acc[3], 0, 0, 0);
            acc[4] = __builtin_amdgcn_mfma_f32_16x16x32_bf16(f2, f1, acc[4], 0, 0, 0);
            acc[5] = __builtin_amdgcn_mfma_f32_16x16x32_bf16(f2, f2, acc[5], 0, 0, 0);
        }
        buf ^= 1;
    }

    // cross-wave reduce: C/D layout col=lane&15, row=(lane>>4)*4+reg [m89/m91]
    __syncthreads();
    #pragma unroll
    for (int w = 0; w < 4; ++w) {
        if (wave == w) {
            #pragma unroll
            for (int t6 = 0; t6 < 6; ++t6) {
                const int t = (t6 < 1) ? 0 : (t6 < 3) ? 1 : 2;                  // tile row
                const int u = (t6 == 0) ? 0 : (t6 < 3) ? (t6 - 1) : (t6 - 3);  // tile col
                #pragma unroll
                for (int r = 0; r < 4; ++r) {
                    const int gi = 16 * t + 4 * fq + r;
                    const int gj = 16 * u + fcol;
                    gsum[gi * GP + gj] += acc[t6][r];
                }
            }
        }
        __syncthreads();
    }

    float* Gb = G + (size_t)b * GSZ;
    for (int idx = tid; idx < GSZ; idx += 256) {
        const int gi = idx / GP, gj = idx % GP;
        if (gj <= gi && gi < (DE + SV)) atomicAdd(&Gb[idx], gsum[idx]);  // 990/block, 128 blocks/batch
    }
}

// out = sum_b sum_{i>=j} w * sign * G[b][i][j]^2 / (B*N); w=1 diag else 2;
// sign=+1 same block (EE/VV), -1 mixed.
__global__ __launch_bounds__(256) void finish_kernel(const float* __restrict__ G,
                                                     float* __restrict__ out) {
    const int tid = threadIdx.x;
    float sum = 0.f;
    for (int idx = tid; idx < BATCHES * GSZ; idx += 256) {
        const int ij = idx % GSZ;
        const int gi = ij / GP;
        const int gj = ij % GP;
        if (gj > gi || gi >= (DE + SV)) continue;
        const float g = G[idx];
        const float w = (gi == gj) ? 1.f : 2.f;
        const float sgn = ((gi < DE) == (gj < DE)) ? 1.f : -1.f;
        sum += w * sgn * g * g;
    }
    #pragma unroll
    for (int o = 32; o > 0; o >>= 1) sum += __shfl_down(sum, o, 64);
    __shared__ float ws[4];
    if ((tid & 63) == 0) ws[tid >> 6] = sum;
    __syncthreads();
    if (tid == 0) {
        const float t = ws[0] + ws[1] + ws[2] + ws[3];
        out[0] = t / (float)((size_t)BATCHES * NROWS);
    }
}

extern "C" void kernel_launch(void* const* d_in, const int* in_sizes, int n_in,
                              void* d_out, int out_size, void* d_ws, size_t ws_size,
                              hipStream_t stream) {
    const float* E = (const float*)d_in[0];   // embeddings (B,F,T,D) fp32
    const float* V = (const float*)d_in[1];   // assignments (B,F,T,S) fp32
    float* G = (float*)d_ws;                  // B * 48*48 fp32 Gram accumulators

    hipMemsetAsync(G, 0, (size_t)BATCHES * GSZ * sizeof(float), stream);
    gram_kernel<<<BATCHES * CHUNKS, 256, 0, stream>>>(E, V, G);
    finish_kernel<<<1, 256, 0, stream>>>(G, (float*)d_out);
}

// Round 6
// 259.407 us; speedup vs baseline: 3.1518x; 1.0372x over previous
//
#include <hip/hip_runtime.h>
#include <hip/hip_bf16.h>

// B=8, F=256, T=512, D=40, S=4
#define BATCHES 8
#define NROWS (256 * 512)                 // N = F*T = 131072
#define DE 40
#define SV 4
#define GP 48                             // Gram dim: 40 E + 4 V + 4 zero pad
#define GSZ (GP * GP)                     // 2304
#define ROWS_PER_BLOCK 1024
#define CHUNKS (NROWS / ROWS_PER_BLOCK)   // 128 -> grid 1024, 4 blocks/CU
#define RSTAGE 128                        // rows per stage (4 waves x K=32)
#define NSTAGES (ROWS_PER_BLOCK / RSTAGE) // 8
#define COLBYTES 256                      // RSTAGE * 2 B bf16, column-major
#define TILEBYTES (GP * COLBYTES)         // 12288 per buffer

typedef __attribute__((ext_vector_type(8))) short bf16x8;  // MFMA A/B frag
typedef __attribute__((ext_vector_type(4))) float f32x4;   // MFMA C/D frag
typedef __attribute__((ext_vector_type(2))) int i32x2;     // 4 bf16 packed

__device__ __forceinline__ int pk_bf16(float lo, float hi) {
    __hip_bfloat162 h2 = __float22bfloat162_rn(float2{lo, hi});  // RNE packed cvt
    return *reinterpret_cast<int*>(&h2);
}

// One barrier per stage: iter s = compute(buf s&1) -> ds_write s+1 (buf (s+1)&1)
// -> global prefetch s+2 -> __syncthreads(). Partial Gram stored flat (no atomics).
__global__ __launch_bounds__(256, 4) void gram_kernel(const float* __restrict__ E,
                                                      const float* __restrict__ V,
                                                      float* __restrict__ P) {
    __shared__ __align__(16) char tb[2][TILEBYTES];
    __shared__ float gsum[GSZ];

    const int tid = threadIdx.x;
    const int lane = tid & 63;
    const int wave = tid >> 6;            // K-chunk: rows 32*wave.. of stage
    const int b = blockIdx.x / CHUNKS;
    const int chunk = blockIdx.x % CHUNKS;
    const size_t row0 = (size_t)chunk * ROWS_PER_BLOCK;

    const float4* __restrict__ Eg = (const float4*)(E + (size_t)b * NROWS * DE) + row0 * 10;
    const float4* __restrict__ Vg = (const float4*)(V + (size_t)b * NROWS * SV) + row0;

    for (int i = tid; i < GSZ; i += 256) gsum[i] = 0.f;
    if (tid < 128) {  // zero pad cols 44..47 of both buffers (constant all stages)
        const int bb = tid >> 6, off = (tid & 63) * 16;
        *(float4*)&tb[bb][44 * COLBYTES + off] = make_float4(0.f, 0.f, 0.f, 0.f);
    }

    // Staging slots: slot idx -> cg = idx%11 (0..9 E f4-col, 10 V), rg = idx/11
    // (rows 4rg..4rg+3). Thread owns slot tid, plus tid+256 if tid<96 (352 total).
    const int cgA = tid % 11, rgA = tid / 11;
    const int cgB = (tid + 256) % 11, rgB = (tid + 256) / 11;
    const bool hasB = (tid < 96);
    const bool vA = (cgA == 10), vB = (cgB == 10);
    const int pA = vA ? 1 : 10, cA = vA ? 0 : cgA;   // per-row f4 pitch, f4 col
    const int pB = vB ? 1 : 10, cB = vB ? 0 : cgB;
    const float4* __restrict__ gA = vA ? Vg : Eg;
    const float4* __restrict__ gB = vB ? Vg : Eg;
    const int oA = 4 * rgA * pA + cA;
    const int oB = 4 * rgB * pB + cB;

    f32x4 acc[6];  // lower-tri 16x16 tiles: (0,0)(1,0)(1,1)(2,0)(2,1)(2,2)
    #pragma unroll
    for (int i = 0; i < 6; ++i) acc[i] = (f32x4){0.f, 0.f, 0.f, 0.f};

    const int fcol = lane & 15;
    const int fq = lane >> 4;
    const int foff = ((wave * 64 + fq * 16) + 16 * fcol) & 255;  // swizzled k-byte

    float4 a0, a1, a2, a3, b0, b1, b2, b3;

    // ---- helpers as macros to keep one code path ----
#define LOAD_STAGE(sidx)                                                        \
    {   const int adv = (sidx) * RSTAGE;                                        \
        a0 = gA[oA + adv * pA];            a1 = gA[oA + adv * pA + pA];         \
        a2 = gA[oA + adv * pA + 2 * pA];   a3 = gA[oA + adv * pA + 3 * pA];     \
        if (hasB) {                                                             \
            b0 = gB[oB + adv * pB];          b1 = gB[oB + adv * pB + pB];       \
            b2 = gB[oB + adv * pB + 2 * pB]; b3 = gB[oB + adv * pB + 3 * pB];   \
        } }

#define WRITE_STAGE(bufidx)                                                     \
    {   char* base = tb[bufidx];                                                \
        _Pragma("unroll")                                                       \
        for (int j = 0; j < 4; ++j) {                                           \
            const float f0 = (j==0)?a0.x:(j==1)?a0.y:(j==2)?a0.z:a0.w;          \
            const float f1 = (j==0)?a1.x:(j==1)?a1.y:(j==2)?a1.z:a1.w;          \
            const float f2 = (j==0)?a2.x:(j==1)?a2.y:(j==2)?a2.z:a2.w;          \
            const float f3 = (j==0)?a3.x:(j==1)?a3.y:(j==2)?a3.z:a3.w;          \
            const int col = 4 * cgA + j;                                        \
            const int off = (8 * rgA + 16 * (col & 15)) & 255;                  \
            i32x2 p = { pk_bf16(f0, f1), pk_bf16(f2, f3) };                     \
            *(i32x2*)&base[col * COLBYTES + off] = p;                           \
        }                                                                       \
        if (hasB) {                                                             \
            _Pragma("unroll")                                                   \
            for (int j = 0; j < 4; ++j) {                                       \
                const float f0 = (j==0)?b0.x:(j==1)?b0.y:(j==2)?b0.z:b0.w;      \
                const float f1 = (j==0)?b1.x:(j==1)?b1.y:(j==2)?b1.z:b1.w;      \
                const float f2 = (j==0)?b2.x:(j==1)?b2.y:(j==2)?b2.z:b2.w;      \
                const float f3 = (j==0)?b3.x:(j==1)?b3.y:(j==2)?b3.z:b3.w;      \
                const int col = 4 * cgB + j;                                    \
                const int off = (8 * rgB + 16 * (col & 15)) & 255;              \
                i32x2 p = { pk_bf16(f0, f1), pk_bf16(f2, f3) };                 \
                *(i32x2*)&base[col * COLBYTES + off] = p;                       \
            } } }

    // prologue: stage 0 staged to buf0; stage 1 prefetched to regs
    LOAD_STAGE(0);
    WRITE_STAGE(0);
    LOAD_STAGE(1);
    __syncthreads();

    for (int s = 0; s < NSTAGES; ++s) {
        {   // compute on buf s&1: 3 frag loads + 6 MFMAs (frag = both A and B)
            const char* base = tb[s & 1];
            const bf16x8 f0 = *(const bf16x8*)&base[(0 * 16 + fcol) * COLBYTES + foff];
            const bf16x8 f1 = *(const bf16x8*)&base[(1 * 16 + fcol) * COLBYTES + foff];
            const bf16x8 f2 = *(const bf16x8*)&base[(2 * 16 + fcol) * COLBYTES + foff];
            acc[0] = __builtin_amdgcn_mfma_f32_16x16x32_bf16(f0, f0, acc[0], 0, 0, 0);
            acc[1] = __builtin_amdgcn_mfma_f32_16x16x32_bf16(f1, f0, acc[1], 0, 0, 0);
            acc[2] = __builtin_amdgcn_mfma_f32_16x16x32_bf16(f1, f1, acc[2], 0, 0, 0);
            acc[3] = __builtin_amdgcn_mfma_f32_16x16x32_bf16(f2, f0, acc[3], 0, 0, 0);
            acc[4] = __builtin_amdgcn_mfma_f32_16x16x32_bf16(f2, f1, acc[4], 0, 0, 0);
            acc[5] = __builtin_amdgcn_mfma_f32_16x16x32_bf16(f2, f2, acc[5], 0, 0, 0);
        }
        if (s + 1 < NSTAGES) WRITE_STAGE((s + 1) & 1);   // regs (stage s+1) -> other buf
        if (s + 2 < NSTAGES) LOAD_STAGE(s + 2);          // prefetch s+2 -> regs
        __syncthreads();  // covers: computes of buf s&1 done AND writes of buf (s+1)&1 done
    }

    // cross-wave merge into gsum: C/D layout col=lane&15, row=(lane>>4)*4+reg [m89/m91]
    #pragma unroll
    for (int w = 0; w < 4; ++w) {
        if (wave == w) {
            #pragma unroll
            for (int t6 = 0; t6 < 6; ++t6) {
                const int t = (t6 < 1) ? 0 : (t6 < 3) ? 1 : 2;
                const int u = (t6 == 0) ? 0 : (t6 < 3) ? (t6 - 1) : (t6 - 3);
                #pragma unroll
                for (int r = 0; r < 4; ++r) {
                    const int gi = 16 * t + 4 * fq + r;
                    const int gj = 16 * u + fcol;
                    gsum[gi * GP + gj] += acc[t6][r];
                }
            }
        }
        __syncthreads();
    }

    // contention-free partial store: P[block][2304], coalesced float4
    const float4* gs4 = (const float4*)gsum;
    float4* P4 = (float4*)(P + (size_t)blockIdx.x * GSZ);
    for (int i = tid; i < GSZ / 4; i += 256) P4[i] = gs4[i];
}

// Sum the 128 chunk-partials per (batch, entry), apply mask, reduce to out[0].
// Grid: BATCHES * (GSZ/256) = 8 * 9 = 72 blocks. out must be zeroed beforehand.
__global__ __launch_bounds__(256) void reduce_finish(const float* __restrict__ P,
                                                     float* __restrict__ out) {
    const int tid = threadIdx.x;
    const int b = blockIdx.x / (GSZ / 256);
    const int e = (blockIdx.x % (GSZ / 256)) * 256 + tid;   // 0..2303

    float g = 0.f;
    const float* base = P + (size_t)b * CHUNKS * GSZ + e;
    #pragma unroll 4
    for (int c = 0; c < CHUNKS; ++c) g += base[(size_t)c * GSZ];  // coalesced per c

    const int gi = e / GP, gj = e % GP;
    float contrib = 0.f;
    if (gi < (DE + SV) && gj <= gi) {
        const float w = (gi == gj) ? 1.f : 2.f;                       // off-diag counted twice
        const float sgn = ((gi < DE) == (gj < DE)) ? 1.f : -1.f;      // EE/VV +, mixed -
        contrib = w * sgn * g * g;
    }
    #pragma unroll
    for (int o = 32; o > 0; o >>= 1) contrib += __shfl_down(contrib, o, 64);
    __shared__ float ws4[4];
    if ((tid & 63) == 0) ws4[tid >> 6] = contrib;
    __syncthreads();
    if (tid == 0) {
        const float t = ws4[0] + ws4[1] + ws4[2] + ws4[3];
        atomicAdd(out, t * (1.f / ((float)BATCHES * (float)NROWS)));  // 72 atomics total
    }
}

extern "C" void kernel_launch(void* const* d_in, const int* in_sizes, int n_in,
                              void* d_out, int out_size, void* d_ws, size_t ws_size,
                              hipStream_t stream) {
    const float* E = (const float*)d_in[0];   // embeddings (B,F,T,D) fp32
    const float* V = (const float*)d_in[1];   // assignments (B,F,T,S) fp32
    float* P = (float*)d_ws;                  // 1024 x 2304 fp32 partial Grams (9.4 MB)

    hipMemsetAsync(d_out, 0, sizeof(float), stream);
    gram_kernel<<<BATCHES * CHUNKS, 256, 0, stream>>>(E, V, P);
    reduce_finish<<<BATCHES * (GSZ / 256), 256, 0, stream>>>(P, (float*)d_out);
}

// Round 7
// 255.346 us; speedup vs baseline: 3.2019x; 1.0159x over previous
//
#include <hip/hip_runtime.h>
#include <hip/hip_bf16.h>

// B=8, F=256, T=512, D=40, S=4
#define BATCHES 8
#define NROWS (256 * 512)                 // N = F*T = 131072
#define DE 40
#define SV 4
#define GP 48                             // Gram dim: 40 E + 4 V + 4 zero pad
#define GSZ (GP * GP)                     // 2304
#define ROWS_PER_BLOCK 1024
#define CHUNKS (NROWS / ROWS_PER_BLOCK)   // 128 -> grid 1024, 4 blocks/CU (LDS-limited)
#define RSTAGE 128                        // rows per stage (4 waves x K=32)
#define NSTAGES (ROWS_PER_BLOCK / RSTAGE) // 8
#define COLBYTES 256                      // RSTAGE * 2 B bf16, column-major
#define TILEBYTES (GP * COLBYTES)         // 12288 per buffer

typedef __attribute__((ext_vector_type(8))) short bf16x8;  // MFMA A/B frag
typedef __attribute__((ext_vector_type(4))) float f32x4;   // MFMA C/D frag
typedef __attribute__((ext_vector_type(2))) int i32x2;     // 4 bf16 packed

__device__ __forceinline__ int pk_bf16(float lo, float hi) {
    __hip_bfloat162 h2 = __float22bfloat162_rn(float2{lo, hi});  // RNE packed cvt
    return *reinterpret_cast<int*>(&h2);
}

struct ARegs { float4 a0, a1, a2, a3; };

// Deep pipeline: A-slot loads get 2 iterations of slack (dual reg sets),
// B-slot (tid<96 extra slot) keeps 1 iteration. One barrier per stage.
__global__ __launch_bounds__(256, 4) void gram_kernel(const float* __restrict__ E,
                                                      const float* __restrict__ V,
                                                      float* __restrict__ P) {
    __shared__ __align__(16) char tb[2][TILEBYTES];
    __shared__ float gsum[GSZ];

    const int tid = threadIdx.x;
    const int lane = tid & 63;
    const int wave = tid >> 6;            // K-chunk: rows 32*wave.. of stage
    const int b = blockIdx.x / CHUNKS;
    const int chunk = blockIdx.x % CHUNKS;
    const size_t row0 = (size_t)chunk * ROWS_PER_BLOCK;

    const float4* __restrict__ Eg = (const float4*)(E + (size_t)b * NROWS * DE) + row0 * 10;
    const float4* __restrict__ Vg = (const float4*)(V + (size_t)b * NROWS * SV) + row0;

    for (int i = tid; i < GSZ; i += 256) gsum[i] = 0.f;
    if (tid < 128) {  // zero pad cols 44..47 of both buffers (constant all stages)
        const int bb = tid >> 6, off = (tid & 63) * 16;
        *(float4*)&tb[bb][44 * COLBYTES + off] = make_float4(0.f, 0.f, 0.f, 0.f);
    }

    // Slots: idx -> cg = idx%11 (0..9 E f4-col, 10 V), rg = idx/11 (rows 4rg..4rg+3).
    // Thread owns slot tid (A), plus slot tid+256 if tid<96 (B). 352 slots total.
    const int cgA = tid % 11, rgA = tid / 11;
    const int cgB = (tid + 256) % 11, rgB = (tid + 256) / 11;
    const bool hasB = (tid < 96);
    const bool vA = (cgA == 10), vB = (cgB == 10);
    const int pA = vA ? 1 : 10, cA = vA ? 0 : cgA;   // per-row f4 pitch, f4 col
    const int pB = vB ? 1 : 10, cB = vB ? 0 : cgB;
    const float4* __restrict__ gA = vA ? Vg : Eg;
    const float4* __restrict__ gB = vB ? Vg : Eg;
    const int oA = 4 * rgA * pA + cA;
    const int oB = 4 * rgB * pB + cB;

    f32x4 acc[6];  // lower-tri 16x16 tiles: (0,0)(1,0)(1,1)(2,0)(2,1)(2,2)
    #pragma unroll
    for (int i = 0; i < 6; ++i) acc[i] = (f32x4){0.f, 0.f, 0.f, 0.f};

    const int fcol = lane & 15;
    const int fq = lane >> 4;
    const int foff = ((wave * 64 + fq * 16) + 16 * fcol) & 255;  // swizzled k-byte

    ARegs A[2];
    float4 b0, b1, b2, b3;

    auto load_a = [&](ARegs& r, int sidx) {
        const int adv = sidx * RSTAGE;
        r.a0 = gA[oA + adv * pA];          r.a1 = gA[oA + adv * pA + pA];
        r.a2 = gA[oA + adv * pA + 2 * pA]; r.a3 = gA[oA + adv * pA + 3 * pA];
    };
    auto load_b = [&](int sidx) {
        if (!hasB) return;
        const int adv = sidx * RSTAGE;
        b0 = gB[oB + adv * pB];          b1 = gB[oB + adv * pB + pB];
        b2 = gB[oB + adv * pB + 2 * pB]; b3 = gB[oB + adv * pB + 3 * pB];
    };
    auto write_stage = [&](const ARegs& r, int bufidx) {
        char* base = tb[bufidx];
        #pragma unroll
        for (int j = 0; j < 4; ++j) {
            const float f0 = (j == 0) ? r.a0.x : (j == 1) ? r.a0.y : (j == 2) ? r.a0.z : r.a0.w;
            const float f1 = (j == 0) ? r.a1.x : (j == 1) ? r.a1.y : (j == 2) ? r.a1.z : r.a1.w;
            const float f2 = (j == 0) ? r.a2.x : (j == 1) ? r.a2.y : (j == 2) ? r.a2.z : r.a2.w;
            const float f3 = (j == 0) ? r.a3.x : (j == 1) ? r.a3.y : (j == 2) ? r.a3.z : r.a3.w;
            const int col = 4 * cgA + j;
            const int off = (8 * rgA + 16 * (col & 15)) & 255;
            i32x2 p = { pk_bf16(f0, f1), pk_bf16(f2, f3) };
            *(i32x2*)&base[col * COLBYTES + off] = p;
        }
        if (hasB) {
            #pragma unroll
            for (int j = 0; j < 4; ++j) {
                const float f0 = (j == 0) ? b0.x : (j == 1) ? b0.y : (j == 2) ? b0.z : b0.w;
                const float f1 = (j == 0) ? b1.x : (j == 1) ? b1.y : (j == 2) ? b1.z : b1.w;
                const float f2 = (j == 0) ? b2.x : (j == 1) ? b2.y : (j == 2) ? b2.z : b2.w;
                const float f3 = (j == 0) ? b3.x : (j == 1) ? b3.y : (j == 2) ? b3.z : b3.w;
                const int col = 4 * cgB + j;
                const int off = (8 * rgB + 16 * (col & 15)) & 255;
                i32x2 p = { pk_bf16(f0, f1), pk_bf16(f2, f3) };
                *(i32x2*)&base[col * COLBYTES + off] = p;
            }
        }
    };

    // prologue: stage 0 staged; A stages 1,2 and B stage 1 in flight
    load_a(A[0], 0);
    load_b(0);
    write_stage(A[0], 0);
    load_a(A[1], 1);
    load_b(1);
    load_a(A[0], 2);   // A[0] free after write_stage(0)
    __syncthreads();

    for (int s = 0; s < NSTAGES; ++s) {
        {   // compute on buf s&1: 3 frag loads + 6 MFMAs (frag = both A and B operand)
            const char* base = tb[s & 1];
            const bf16x8 f0 = *(const bf16x8*)&base[(0 * 16 + fcol) * COLBYTES + foff];
            const bf16x8 f1 = *(const bf16x8*)&base[(1 * 16 + fcol) * COLBYTES + foff];
            const bf16x8 f2 = *(const bf16x8*)&base[(2 * 16 + fcol) * COLBYTES + foff];
            acc[0] = __builtin_amdgcn_mfma_f32_16x16x32_bf16(f0, f0, acc[0], 0, 0, 0);
            acc[1] = __builtin_amdgcn_mfma_f32_16x16x32_bf16(f1, f0, acc[1], 0, 0, 0);
            acc[2] = __builtin_amdgcn_mfma_f32_16x16x32_bf16(f1, f1, acc[2], 0, 0, 0);
            acc[3] = __builtin_amdgcn_mfma_f32_16x16x32_bf16(f2, f0, acc[3], 0, 0, 0);
            acc[4] = __builtin_amdgcn_mfma_f32_16x16x32_bf16(f2, f1, acc[4], 0, 0, 0);
            acc[5] = __builtin_amdgcn_mfma_f32_16x16x32_bf16(f2, f2, acc[5], 0, 0, 0);
        }
        if (s + 1 < NSTAGES) write_stage(A[(s + 1) & 1], (s + 1) & 1);  // stage s+1 -> other buf
        if (s + 3 < NSTAGES) load_a(A[(s + 1) & 1], s + 3);             // refill freed A set
        if (s + 2 < NSTAGES) load_b(s + 2);
        __syncthreads();  // computes of buf s&1 done AND writes of buf (s+1)&1 done
    }

    // cross-wave merge into gsum: C/D layout col=lane&15, row=(lane>>4)*4+reg [m89/m91]
    #pragma unroll
    for (int w = 0; w < 4; ++w) {
        if (wave == w) {
            #pragma unroll
            for (int t6 = 0; t6 < 6; ++t6) {
                const int t = (t6 < 1) ? 0 : (t6 < 3) ? 1 : 2;
                const int u = (t6 == 0) ? 0 : (t6 < 3) ? (t6 - 1) : (t6 - 3);
                #pragma unroll
                for (int r = 0; r < 4; ++r) {
                    const int gi = 16 * t + 4 * fq + r;
                    const int gj = 16 * u + fcol;
                    gsum[gi * GP + gj] += acc[t6][r];
                }
            }
        }
        __syncthreads();
    }

    // contention-free partial store: P[block][2304], coalesced float4
    const float4* gs4 = (const float4*)gsum;
    float4* P4 = (float4*)(P + (size_t)blockIdx.x * GSZ);
    for (int i = tid; i < GSZ / 4; i += 256) P4[i] = gs4[i];
}

// Sum the 128 chunk-partials per (batch, entry), apply mask, reduce to out[0].
// Grid: BATCHES * 36 = 288 blocks; block owns 64 entries, 4-way chunk split.
__global__ __launch_bounds__(256) void reduce_finish(const float* __restrict__ P,
                                                     float* __restrict__ out) {
    const int tid = threadIdx.x;
    const int b = blockIdx.x / 36;
    const int e0 = (blockIdx.x % 36) * 64;
    const int cs = tid / 64;            // chunk strip 0..3
    const int el = tid % 64;            // entry within strip
    const int e = e0 + el;

    float g = 0.f;
    const float* base = P + (size_t)b * CHUNKS * GSZ + e;
    #pragma unroll 4
    for (int c = cs; c < CHUNKS; c += 4) g += base[(size_t)c * GSZ];  // 256B/wave coalesced

    __shared__ float part[4][64];
    part[cs][el] = g;
    __syncthreads();

    float contrib = 0.f;
    if (tid < 64) {
        g = part[0][el] + part[1][el] + part[2][el] + part[3][el];
        const int gi = e / GP, gj = e % GP;
        if (gi < (DE + SV) && gj <= gi) {
            const float w = (gi == gj) ? 1.f : 2.f;                   // off-diag counted twice
            const float sgn = ((gi < DE) == (gj < DE)) ? 1.f : -1.f;  // EE/VV +, mixed -
            contrib = w * sgn * g * g;
        }
        #pragma unroll
        for (int o = 32; o > 0; o >>= 1) contrib += __shfl_down(contrib, o, 64);
        if (tid == 0)
            atomicAdd(out, contrib * (1.f / ((float)BATCHES * (float)NROWS)));  // 288 atomics
    }
}

extern "C" void kernel_launch(void* const* d_in, const int* in_sizes, int n_in,
                              void* d_out, int out_size, void* d_ws, size_t ws_size,
                              hipStream_t stream) {
    const float* E = (const float*)d_in[0];   // embeddings (B,F,T,D) fp32
    const float* V = (const float*)d_in[1];   // assignments (B,F,T,S) fp32
    float* P = (float*)d_ws;                  // 1024 x 2304 fp32 partial Grams (9.4 MB)

    hipMemsetAsync(d_out, 0, sizeof(float), stream);
    gram_kernel<<<BATCHES * CHUNKS, 256, 0, stream>>>(E, V, P);
    reduce_finish<<<BATCHES * 36, 256, 0, stream>>>(P, (float*)d_out);
}